// Round 1
// baseline (142.322 us; speedup 1.0000x reference)
//
#include <hip/hip_runtime.h>
#include <math.h>

// Gaussians covariance kernel, MI355X (gfx950).
//
// Key algebraic simplification: scales are isotropic per point
// (scales[n] = s * ones(3)), so cov = s^2 * R * R^T = s^2 * I for the
// rotation R built from the normalized quaternion. Off-diagonal terms in
// the reference are pure fp rounding (~1e-13) vs threshold ~3e-8, so we
// only need s^2 on the diagonal. The real work is the 3-nearest-neighbor
// search over all N^2 pairs.

#define N_PTS  12288
#define BI     32                 // i-points per block
#define SPLITS 32                 // j-range splits per block
#define BLOCK  (BI * SPLITS)      // 1024 threads
#define JCHUNK (N_PTS / SPLITS)   // 384 j's per thread

__global__ __launch_bounds__(BLOCK) void gauss_cov_kernel(
    const float* __restrict__ pts, float* __restrict__ out)
{
    const int t     = threadIdx.x;
    const int il    = t & (BI - 1);   // which of the 32 i's in this block
    const int split = t >> 5;         // which j-split (0..31)
    const int i     = blockIdx.x * BI + il;

    const float px = pts[3 * i + 0];
    const float py = pts[3 * i + 1];
    const float pz = pts[3 * i + 2];

    // a0 <= a1 <= a2 : three smallest squared distances seen so far
    float a0 = INFINITY, a1 = INFINITY, a2 = INFINITY;

    const int j0 = split * JCHUNK;
    #pragma unroll 4
    for (int jl = 0; jl < JCHUNK; ++jl) {
        const int j = j0 + jl;
        const float x = pts[3 * j + 0];
        const float y = pts[3 * j + 1];
        const float z = pts[3 * j + 2];
        const float dx = px - x, dy = py - y, dz = pz - z;
        float d2 = dx * dx;
        d2 = fmaf(dy, dy, d2);
        d2 = fmaf(dz, dz, d2);
        const float d = (j == i) ? INFINITY : d2;   // exclude diagonal
        // branchless sorted insert: keep 3 smallest of {a0,a1,a2,d}
        const float m  = fminf(a2, d);
        const float t1 = fminf(a1, m);
        a2 = fmaxf(a1, m);
        const float t0 = fminf(a0, t1);
        a1 = fmaxf(a0, t1);
        a0 = t0;
    }

    // merge the 32 splits' top-3 per i through LDS
    __shared__ float s3[SPLITS][BI][3];   // 12 KB
    s3[split][il][0] = a0;
    s3[split][il][1] = a1;
    s3[split][il][2] = a2;
    __syncthreads();

    if (t < BI) {
        float b0 = INFINITY, b1 = INFINITY, b2 = INFINITY;
        for (int s = 0; s < SPLITS; ++s) {
            #pragma unroll
            for (int k = 0; k < 3; ++k) {
                const float d  = s3[s][t][k];
                const float m  = fminf(b2, d);
                const float t1 = fminf(b1, m);
                b2 = fmaxf(b1, m);
                const float t0 = fminf(b0, t1);
                b1 = fmaxf(b0, t1);
                b0 = t0;
            }
        }
        const float d0 = sqrtf(fmaxf(b0, 0.0f));
        const float d1 = sqrtf(fmaxf(b1, 0.0f));
        const float d2 = sqrtf(fmaxf(b2, 0.0f));
        float mean = (d0 + d1 + d2) * (1.0f / 3.0f);
        mean = fmaxf(mean, 1e-5f);
        const float s  = 0.001f * mean;
        const float s2 = s * s;

        const int ii = blockIdx.x * BI + t;
        float* o = out + (size_t)ii * 9;
        o[0] = s2;  o[1] = 0.0f; o[2] = 0.0f;
        o[3] = 0.0f; o[4] = s2;  o[5] = 0.0f;
        o[6] = 0.0f; o[7] = 0.0f; o[8] = s2;
    }
}

extern "C" void kernel_launch(void* const* d_in, const int* in_sizes, int n_in,
                              void* d_out, int out_size, void* d_ws, size_t ws_size,
                              hipStream_t stream) {
    const float* pts = (const float*)d_in[0];   // (N, 3) float32
    // d_in[1] = quaternions: algebraically irrelevant (cov = s^2 * I)
    float* out = (float*)d_out;                 // (N, 3, 3) float32
    gauss_cov_kernel<<<dim3(N_PTS / BI), dim3(BLOCK), 0, stream>>>(pts, out);
}

// Round 2
// 105.564 us; speedup vs baseline: 1.3482x; 1.3482x over previous
//
#include <hip/hip_runtime.h>
#include <math.h>

// Gaussians covariance kernel, MI355X (gfx950).
//
// cov = s^2 * I exactly (isotropic scales, R orthogonal); the work is the
// exact 3-NN search over all N^2 pairs.
//
// Round-2 optimizations vs R1 (98.4 us, VALUBusy 61%, occ 46%):
//  - top-4 sorted insert via v_med3_f32 (5 ops), diagonal handled as the
//    known exact-zero minimum and dropped post-merge -> 11 VALU/pair (was 13)
//  - float4 global loads: 3x dwordx4 per 4 points (was 12 scalar loads)
//  - balanced grid: 512 blocks x 768 threads = exactly 2 blocks/CU

#define N_PTS  12288
#define BI     24                  // i-points per block
#define SPLITS 32                  // j-splits per block
#define BLOCK  (BI * SPLITS)       // 768 threads = 12 waves
#define JCHUNK (N_PTS / SPLITS)    // 384 j's per thread
#define GROUPS (JCHUNK / 4)        // 96 float4-groups

__device__ __forceinline__ void ins4(float d, float& a0, float& a1,
                                     float& a2, float& a3) {
    // sorted insert of d into a0<=a1<=a2<=a3, keep 4 smallest (5 VALU ops)
    const float n0 = fminf(a0, d);
    const float n1 = __builtin_amdgcn_fmed3f(a0, a1, d);
    const float n2 = __builtin_amdgcn_fmed3f(a1, a2, d);
    const float n3 = fminf(a3, fmaxf(a2, d));
    a0 = n0; a1 = n1; a2 = n2; a3 = n3;
}

__device__ __forceinline__ float dist2(float px, float py, float pz,
                                       float x, float y, float z) {
    const float dx = px - x, dy = py - y, dz = pz - z;
    return fmaf(dz, dz, fmaf(dy, dy, dx * dx));
}

__global__ __launch_bounds__(BLOCK) void gauss_cov_kernel(
    const float* __restrict__ pts, float* __restrict__ out)
{
    const int t     = threadIdx.x;
    const int il    = t % BI;
    const int split = t / BI;
    const int i     = blockIdx.x * BI + il;

    const float px = pts[3 * i + 0];
    const float py = pts[3 * i + 1];
    const float pz = pts[3 * i + 2];

    // four smallest squared distances (diagonal contributes an exact 0)
    float a0 = INFINITY, a1 = INFINITY, a2 = INFINITY, a3 = INFINITY;

    const float4* __restrict__ p4 = (const float4*)pts;
    const int base = (split * JCHUNK * 3) / 4;   // 16B-aligned chunk start

    #pragma unroll 2
    for (int g = 0; g < GROUPS; ++g) {
        const float4 A = p4[base + 3 * g + 0];   // x0 y0 z0 x1
        const float4 B = p4[base + 3 * g + 1];   // y1 z1 x2 y2
        const float4 C = p4[base + 3 * g + 2];   // z2 x3 y3 z3
        ins4(dist2(px, py, pz, A.x, A.y, A.z), a0, a1, a2, a3);
        ins4(dist2(px, py, pz, A.w, B.x, B.y), a0, a1, a2, a3);
        ins4(dist2(px, py, pz, B.z, B.w, C.x), a0, a1, a2, a3);
        ins4(dist2(px, py, pz, C.y, C.z, C.w), a0, a1, a2, a3);
    }

    __shared__ float s4[SPLITS][BI][4];   // 12 KB
    s4[split][il][0] = a0;
    s4[split][il][1] = a1;
    s4[split][il][2] = a2;
    s4[split][il][3] = a3;
    __syncthreads();

    if (t < BI) {
        float b0 = INFINITY, b1 = INFINITY, b2 = INFINITY, b3 = INFINITY;
        for (int s = 0; s < SPLITS; ++s) {
            #pragma unroll
            for (int k = 0; k < 4; ++k)
                ins4(s4[s][t][k], b0, b1, b2, b3);
        }
        // b0 == 0 is the diagonal; true 3-NN squared distances are b1,b2,b3
        const float d0 = sqrtf(fmaxf(b1, 0.0f));
        const float d1 = sqrtf(fmaxf(b2, 0.0f));
        const float d2 = sqrtf(fmaxf(b3, 0.0f));
        float mean = (d0 + d1 + d2) * (1.0f / 3.0f);
        mean = fmaxf(mean, 1e-5f);
        const float s  = 0.001f * mean;
        const float s2 = s * s;

        float* o = out + (size_t)(blockIdx.x * BI + t) * 9;
        o[0] = s2;   o[1] = 0.0f; o[2] = 0.0f;
        o[3] = 0.0f; o[4] = s2;   o[5] = 0.0f;
        o[6] = 0.0f; o[7] = 0.0f; o[8] = s2;
    }
}

extern "C" void kernel_launch(void* const* d_in, const int* in_sizes, int n_in,
                              void* d_out, int out_size, void* d_ws, size_t ws_size,
                              hipStream_t stream) {
    const float* pts = (const float*)d_in[0];   // (N, 3) float32
    // d_in[1] = quaternions: algebraically irrelevant (cov = s^2 * I)
    float* out = (float*)d_out;                 // (N, 3, 3) float32
    gauss_cov_kernel<<<dim3(N_PTS / BI), dim3(BLOCK), 0, stream>>>(pts, out);
}

// Round 3
// 87.763 us; speedup vs baseline: 1.6217x; 1.2028x over previous
//
#include <hip/hip_runtime.h>
#include <math.h>

// Gaussians covariance, MI355X. cov = s^2 * I exactly (isotropic scales,
// R orthogonal) -> problem is the exact 3-NN search over N^2 pairs.
//
// R3 structure (vs R2: 60.7us, VALUBusy 68%):
//  - wave-uniform j: all 64 lanes scan the same LDS-staged j stream
//    (broadcast ds_read_b128, immediate offsets, zero addr VALU in loop)
//  - gram distance d^2/2 = qi + (J.w - p.pj), J.w = ||pj||^2/2 staged in
//    LDS alongside coords: 3 fma (free -src modifier) + 1 add per pair
//  - diagonal blocks (i-tile inside j-chunk, 1/16 of blocks) keep top-4
//    (exact-0 self-distance takes a slot, dropped at merge); others top-3
//  - grid 48 x 16 = 768 blocks x 256 thr = exactly 3 blocks/CU, balanced
//  - partial top-4 per (i, split) -> d_ws (3 MB), tiny merge kernel

#define N_PTS  12288
#define ITILE  256                 // i's per block
#define GSPLIT 16                  // global j splits
#define JCH    (N_PTS / GSPLIT)    // 768 j's per block

__device__ __forceinline__ void ins4(float d, float& a0, float& a1,
                                     float& a2, float& a3) {
    // insert d into sorted a0<=a1<=a2<=a3, keep 4 smallest (5 VALU)
    const float n0 = fminf(a0, d);
    const float n1 = __builtin_amdgcn_fmed3f(a0, a1, d);
    const float n2 = __builtin_amdgcn_fmed3f(a1, a2, d);
    const float n3 = fminf(a3, fmaxf(a2, d));
    a0 = n0; a1 = n1; a2 = n2; a3 = n3;
}

__device__ __forceinline__ void ins3(float d, float& a0, float& a1, float& a2) {
    // insert d into sorted a0<=a1<=a2, keep 3 smallest (4 VALU)
    const float n0 = fminf(a0, d);
    const float n1 = __builtin_amdgcn_fmed3f(a0, a1, d);
    const float n2 = fminf(a2, fmaxf(a1, d));
    a0 = n0; a1 = n1; a2 = n2;
}

__global__ __launch_bounds__(ITILE) void knn_partial(
    const float* __restrict__ pts, float4* __restrict__ ws4)
{
    __shared__ float4 sj[JCH];     // 12 KB: (x, y, z, 0.5*|p|^2) per j
    const int t  = threadIdx.x;
    const int it = blockIdx.x;     // i-tile 0..47
    const int g  = blockIdx.y;     // j-split 0..15

    // stage j-chunk into LDS (3 iters/thread, coalesced dword reads)
    for (int k = t; k < JCH; k += ITILE) {
        const int j = g * JCH + k;
        const float x = pts[3 * j + 0];
        const float y = pts[3 * j + 1];
        const float z = pts[3 * j + 2];
        sj[k] = make_float4(x, y, z, 0.5f * fmaf(z, z, fmaf(y, y, x * x)));
    }

    const int   i  = it * ITILE + t;
    const float px = pts[3 * i + 0];
    const float py = pts[3 * i + 1];
    const float pz = pts[3 * i + 2];
    // same op order as staging -> diagonal residual ~1 ulp
    const float qi = 0.5f * fmaf(pz, pz, fmaf(py, py, px * px));
    __syncthreads();

    float a0 = INFINITY, a1 = INFINITY, a2 = INFINITY, a3 = INFINITY;

    if (it / 3 == g) {
        // diagonal j==i is in this chunk: its d2h ~ 0 occupies one of 4 slots
        #pragma unroll 8
        for (int k = 0; k < JCH; ++k) {
            const float4 J = sj[k];
            float acc = fmaf(-J.x, px, J.w);
            acc = fmaf(-J.y, py, acc);
            acc = fmaf(-J.z, pz, acc);
            ins4(qi + acc, a0, a1, a2, a3);   // half squared distance
        }
    } else {
        #pragma unroll 8
        for (int k = 0; k < JCH; ++k) {
            const float4 J = sj[k];
            float acc = fmaf(-J.x, px, J.w);
            acc = fmaf(-J.y, py, acc);
            acc = fmaf(-J.z, pz, acc);
            ins3(qi + acc, a0, a1, a2);       // a3 stays INF
        }
    }

    ws4[g * N_PTS + i] = make_float4(a0, a1, a2, a3);   // coalesced 16B
}

__global__ __launch_bounds__(256) void knn_merge(
    const float4* __restrict__ ws4, float* __restrict__ out)
{
    const int i = blockIdx.x * 256 + threadIdx.x;
    float b0 = INFINITY, b1 = INFINITY, b2 = INFINITY, b3 = INFINITY;
    #pragma unroll
    for (int g = 0; g < GSPLIT; ++g) {
        const float4 v = ws4[g * N_PTS + i];   // coalesced across lanes
        ins4(v.x, b0, b1, b2, b3);
        ins4(v.y, b0, b1, b2, b3);
        ins4(v.z, b0, b1, b2, b3);
        ins4(v.w, b0, b1, b2, b3);
    }
    // b0 ~ 0 is the diagonal; b1..b3 are the 3-NN half squared distances
    const float d0 = sqrtf(fmaxf(b1 + b1, 0.0f));
    const float d1 = sqrtf(fmaxf(b2 + b2, 0.0f));
    const float d2 = sqrtf(fmaxf(b3 + b3, 0.0f));
    float mean = fmaxf((d0 + d1 + d2) * (1.0f / 3.0f), 1e-5f);
    const float s  = 0.001f * mean;
    const float s2 = s * s;

    float* o = out + (size_t)i * 9;
    o[0] = s2;   o[1] = 0.0f; o[2] = 0.0f;
    o[3] = 0.0f; o[4] = s2;   o[5] = 0.0f;
    o[6] = 0.0f; o[7] = 0.0f; o[8] = s2;
}

extern "C" void kernel_launch(void* const* d_in, const int* in_sizes, int n_in,
                              void* d_out, int out_size, void* d_ws, size_t ws_size,
                              hipStream_t stream) {
    const float* pts = (const float*)d_in[0];   // (N, 3) float32
    // d_in[1] = quaternions: algebraically irrelevant (cov = s^2 * I)
    float4* ws4 = (float4*)d_ws;                // needs 16*12288*16B = 3 MB
    float*  out = (float*)d_out;                // (N, 3, 3) float32

    knn_partial<<<dim3(N_PTS / ITILE, GSPLIT), dim3(ITILE), 0, stream>>>(pts, ws4);
    knn_merge<<<dim3(N_PTS / 256), dim3(256), 0, stream>>>(ws4, out);
}